// Round 1
// baseline (1268.236 us; speedup 1.0000x reference)
//
#include <hip/hip_runtime.h>
#include <stdint.h>

typedef unsigned short u16;
typedef unsigned int   u32;
using f32x4  = __attribute__((ext_vector_type(4))) float;
using bf16x8 = __attribute__((ext_vector_type(8))) short;   // 8 bf16 codes (4 VGPRs)

// ---------------- fp32 -> bf16 (RNE) conversion, vectorized ----------------
__device__ __forceinline__ u16 f2bf(float f) {
  union { float f; u32 u; } c; c.f = f;
  return (u16)((c.u + 0x7FFFu + ((c.u >> 16) & 1u)) >> 16);
}

__global__ void cvt_f32_bf16(const float* __restrict__ in, u16* __restrict__ out, int n8) {
  int i = blockIdx.x * blockDim.x + threadIdx.x;
  const int stride = gridDim.x * blockDim.x;
  for (; i < n8; i += stride) {
    float4 v0 = reinterpret_cast<const float4*>(in)[2 * i];
    float4 v1 = reinterpret_cast<const float4*>(in)[2 * i + 1];
    uint4 o;
    o.x = (u32)f2bf(v0.x) | ((u32)f2bf(v0.y) << 16);
    o.y = (u32)f2bf(v0.z) | ((u32)f2bf(v0.w) << 16);
    o.z = (u32)f2bf(v1.x) | ((u32)f2bf(v1.y) << 16);
    o.w = (u32)f2bf(v1.z) | ((u32)f2bf(v1.w) << 16);
    reinterpret_cast<uint4*>(out)[i] = o;
  }
}

// async global->LDS, 16B per lane, dest = wave-uniform base + lane*16
#define GLD_LDS16(SRC, DST)                                      \
  __builtin_amdgcn_global_load_lds(                              \
      (const __attribute__((address_space(1))) void*)(SRC),      \
      (__attribute__((address_space(3))) void*)(DST), 16, 0, 0)

// ---------------- bf16 GEMM: C[M][N] = scale * A[M][K] @ B[N][K]^T + bias ----------------
// 128x128 tile, BK=64, 4 waves (2x2), 64x64 per wave via 4x4 16x16x32 MFMA frags.
// LDS tiles are [128 rows][64 bf16] with XOR slot swizzle: phys_slot = kslot ^ (row&7)
// (8 slots of 16B per 128B row). global_load_lds writes linearly; the source global
// address is pre-swizzled per lane (rule: linear dest + inverse-swz source + swz read).
__global__ __launch_bounds__(256, 2)
void gemm_bf16_scale_bias(const u16* __restrict__ A,   // [M][K] bf16 (x)
                          const u16* __restrict__ B,   // [N][K] bf16 (w)
                          const float* __restrict__ scale_p,
                          const float* __restrict__ bias,
                          float* __restrict__ C,       // [M][N] fp32
                          int Mm, int Nn, int Kk) {
  (void)Mm;
  __shared__ u16 lds[2][2][128 * 64];  // [buf][A/B][tile] = 64 KiB total

  const int tid  = threadIdx.x;
  const int lane = tid & 63;
  const int wave = tid >> 6;       // 0..3
  const int wr = wave >> 1;        // wave row (0..1)
  const int wc = wave & 1;         // wave col (0..1)
  const int m0 = blockIdx.y * 128;
  const int n0 = blockIdx.x * 128;

  // staging decomposition: per gload_lds instr, 64 lanes write 1024B = 8 rows x 128B
  const int rg = lane >> 3;              // row within 8-row group (== row&7)
  const int ss = (lane & 7) ^ rg;        // source logical k-slot (inverse swizzle)

  const u16* ga = A + (size_t)m0 * Kk;
  const u16* gb = B + (size_t)n0 * Kk;

  f32x4 acc[4][4];
#pragma unroll
  for (int i = 0; i < 4; ++i)
#pragma unroll
    for (int j = 0; j < 4; ++j)
      acc[i][j] = (f32x4){0.f, 0.f, 0.f, 0.f};

  const int r16 = lane & 15;   // fragment row/col within 16
  const int kq  = lane >> 4;   // k-quarter (0..3)

  auto stage = [&](int buf, int kt) {
    const u16* at = ga + kt * 64;
    const u16* bt = gb + kt * 64;
    u16* la = &lds[buf][0][0];
    u16* lb = &lds[buf][1][0];
#pragma unroll
    for (int j = 0; j < 4; ++j) {
      const int i   = wave * 4 + j;      // instr index 0..15 (rows i*8..i*8+7)
      const int row = i * 8 + rg;
      GLD_LDS16(at + (size_t)row * Kk + ss * 8, la + i * 512);
      GLD_LDS16(bt + (size_t)row * Kk + ss * 8, lb + i * 512);
    }
  };

  auto compute = [&](int buf) {
    const u16* la = &lds[buf][0][0];
    const u16* lb = &lds[buf][1][0];
#pragma unroll
    for (int ks = 0; ks < 2; ++ks) {     // two K=32 sub-steps of BK=64
      bf16x8 a[4], b[4];
#pragma unroll
      for (int mi = 0; mi < 4; ++mi) {
        const int row  = wr * 64 + mi * 16 + r16;
        const int slot = (ks * 4 + kq) ^ (row & 7);
        a[mi] = *reinterpret_cast<const bf16x8*>(la + row * 64 + slot * 8);
      }
#pragma unroll
      for (int ni = 0; ni < 4; ++ni) {
        const int row  = wc * 64 + ni * 16 + r16;
        const int slot = (ks * 4 + kq) ^ (row & 7);
        b[ni] = *reinterpret_cast<const bf16x8*>(lb + row * 64 + slot * 8);
      }
#pragma unroll
      for (int mi = 0; mi < 4; ++mi)
#pragma unroll
        for (int ni = 0; ni < 4; ++ni)
          acc[mi][ni] = __builtin_amdgcn_mfma_f32_16x16x32_bf16(a[mi], b[ni], acc[mi][ni], 0, 0, 0);
    }
  };

  const int KT = Kk >> 6;   // K / 64
  stage(0, 0);
  __syncthreads();          // drains vmcnt before first compute
  int cur = 0;
  for (int kt = 1; kt < KT; ++kt) {
    stage(cur ^ 1, kt);     // issue next-tile async loads first
    compute(cur);           // ds_read + MFMA on current buffer
    __syncthreads();        // vmcnt(0)+lgkmcnt(0)+barrier: next tile ready, cur free
    cur ^= 1;
  }
  compute(cur);             // epilogue tile (no prefetch)

  // ---- epilogue: out = acc*scale + bias, fp32 ----
  const float sc = scale_p[0];
  float bv[4];
#pragma unroll
  for (int ni = 0; ni < 4; ++ni) bv[ni] = bias[n0 + wc * 64 + ni * 16 + r16];
#pragma unroll
  for (int mi = 0; mi < 4; ++mi) {
#pragma unroll
    for (int r = 0; r < 4; ++r) {
      // C/D layout (16x16x32): col = lane&15, row = (lane>>4)*4 + reg
      const int row = m0 + wr * 64 + mi * 16 + kq * 4 + r;
      float* cp = C + (size_t)row * Nn + (n0 + wc * 64 + r16);
#pragma unroll
      for (int ni = 0; ni < 4; ++ni)
        cp[ni * 16] = acc[mi][ni][r] * sc + bv[ni];
    }
  }
}

extern "C" void kernel_launch(void* const* d_in, const int* in_sizes, int n_in,
                              void* d_out, int out_size, void* d_ws, size_t ws_size,
                              hipStream_t stream) {
  (void)n_in; (void)out_size; (void)ws_size;
  const float* x  = (const float*)d_in[0];   // [M][K] fp32
  const float* w  = (const float*)d_in[1];   // [N][K] fp32 (fp8-representable values)
  const float* sc = (const float*)d_in[2];   // [1]
  const float* bs = (const float*)d_in[3];   // [N]
  float* out = (float*)d_out;                // [M][N] fp32

  const int N = in_sizes[3];        // 16384
  const int K = in_sizes[1] / N;    // 4096
  const int M = in_sizes[0] / K;    // 8192

  u16* xb = (u16*)d_ws;                      // [M][K] bf16  (64 MB)
  u16* wb = xb + (size_t)M * K;              // [N][K] bf16  (128 MB)

  cvt_f32_bf16<<<2048, 256, 0, stream>>>(x, xb, (M * K) / 8);
  cvt_f32_bf16<<<2048, 256, 0, stream>>>(w, wb, (N * K) / 8);

  dim3 grid(N / 128, M / 128);   // (128, 64): x-fastest => n-tiles of one m-panel share A in L2
  gemm_bf16_scale_bias<<<grid, 256, 0, stream>>>(xb, wb, sc, bs, out, M, N, K);
}

// Round 2
// 1044.196 us; speedup vs baseline: 1.2146x; 1.2146x over previous
//
#include <hip/hip_runtime.h>
#include <stdint.h>

typedef unsigned short u16;
typedef unsigned int   u32;
using f32x4  = __attribute__((ext_vector_type(4))) float;
using bf16x8 = __attribute__((ext_vector_type(8))) short;   // 8 bf16 codes (4 VGPRs)

// ---------------- fp32 -> bf16 (RNE) conversion, vectorized ----------------
__device__ __forceinline__ u16 f2bf(float f) {
  union { float f; u32 u; } c; c.f = f;
  return (u16)((c.u + 0x7FFFu + ((c.u >> 16) & 1u)) >> 16);
}

__global__ void cvt_f32_bf16(const float* __restrict__ in, u16* __restrict__ out, int n8) {
  int i = blockIdx.x * blockDim.x + threadIdx.x;
  const int stride = gridDim.x * blockDim.x;
  for (; i < n8; i += stride) {
    float4 v0 = reinterpret_cast<const float4*>(in)[2 * i];
    float4 v1 = reinterpret_cast<const float4*>(in)[2 * i + 1];
    uint4 o;
    o.x = (u32)f2bf(v0.x) | ((u32)f2bf(v0.y) << 16);
    o.y = (u32)f2bf(v0.z) | ((u32)f2bf(v0.w) << 16);
    o.z = (u32)f2bf(v1.x) | ((u32)f2bf(v1.y) << 16);
    o.w = (u32)f2bf(v1.z) | ((u32)f2bf(v1.w) << 16);
    reinterpret_cast<uint4*>(out)[i] = o;
  }
}

// async global->LDS, 16B per lane, dest = wave-uniform base + lane*16
#define GLD_LDS16(SRC, DST)                                      \
  __builtin_amdgcn_global_load_lds(                              \
      (const __attribute__((address_space(1))) void*)(SRC),      \
      (__attribute__((address_space(3))) void*)(DST), 16, 0, 0)

#define SCHED0() __builtin_amdgcn_sched_barrier(0)
#define BAR()    __builtin_amdgcn_s_barrier()
#define PRIO(x)  __builtin_amdgcn_s_setprio(x)

// ---------------- 256x256 8-phase bf16 GEMM: C = scale*(A @ B^T) + bias ----------------
// BM=BN=256, BK=64, 8 waves (2M x 4N), per-wave 128x64 output (8x4 16x16 frags).
// LDS: 2 buf x (A 32KB + B 32KB) = 128 KiB. XOR slot swizzle: phys_slot = kslot ^ (row&7),
// staged via inverse-swizzled global source (global_load_lds writes linearly).
__global__ __launch_bounds__(512, 2)
void gemm256_8ph(const u16* __restrict__ A,   // [M][K] bf16
                 const u16* __restrict__ B,   // [N][K] bf16
                 const float* __restrict__ scale_p,
                 const float* __restrict__ bias,
                 float* __restrict__ C,       // [M][N] fp32
                 int Nn, int Kk, int NT) {
  __shared__ u16 lds[2][2][256 * 64];  // [buf][A/B][256 rows x 64 cols]

  const int tid  = threadIdx.x;
  const int lane = tid & 63;
  const int wave = tid >> 6;       // 0..7
  const int wr = wave >> 2;        // 0..1 (M)
  const int wc = wave & 3;         // 0..3 (N)

  // T1: XCD-aware swizzle (gridDim.x == 2048, divisible by 8)
  const int bid = blockIdx.x;
  const int cpx = gridDim.x >> 3;
  const int wg  = (bid & 7) * cpx + (bid >> 3);
  const int mt = wg / NT, nt = wg % NT;
  const int m0 = mt * 256, n0 = nt * 256;

  const int rg  = lane >> 3;             // row in 8-row staging group
  const int ss  = (lane & 7) ^ rg;       // inverse-swizzled source k-slot
  const int r16 = lane & 15;
  const int kq  = lane >> 4;

  // per-thread global staging bases (row = h*128 + wave*16 + j*8 + rg, col = kt*64 + ss*8)
  const u16* ga = A + ((size_t)m0 + wave * 16 + rg) * Kk + ss * 8;
  const u16* gb = B + ((size_t)n0 + wave * 16 + rg) * Kk + ss * 8;

  // LDS element offsets for fragment reads (slot = (ks*4+kq) ^ (row&7); ks flips bit 5)
  const int aoff = (wr * 128 + r16) * 64 + (kq ^ (r16 & 7)) * 8;  // + mi*1024, ^ (ks*32)
  const int boff = (wc * 64  + r16) * 64 + (kq ^ (r16 & 7)) * 8;  // + ni*1024, ^ (ks*32)

  f32x4 acc[8][4];
#pragma unroll
  for (int i = 0; i < 8; ++i)
#pragma unroll
    for (int j = 0; j < 4; ++j)
      acc[i][j] = (f32x4){0.f, 0.f, 0.f, 0.f};

  bf16x8 af[4][2];   // current mi-group (mh*4 + i), ks 0/1
  bf16x8 bf_[4][2];  // all 4 ni frags, ks 0/1 (live whole K-tile)

  // stage one half-tile: operand op (0=A,1=B), half h, into buffer bf_, source k-tile kt
#define STAGE(bfi_, op_, h_, kt_) do {                                          \
    const u16* _g = ((op_) ? gb : ga) + (size_t)(kt_) * 64 + (size_t)(h_) * 128 * Kk; \
    u16* _d = &lds[bfi_][op_][(h_) * 128 * 64 + wave * 16 * 64];                \
    GLD_LDS16(_g,          _d);                                                 \
    GLD_LDS16(_g + 8 * Kk, _d + 512);                                           \
  } while (0)

#define LDA(i_, mh_) do {                                                       \
    const int _o = aoff + ((mh_) * 4 + (i_)) * 1024;                            \
    af[i_][0] = *reinterpret_cast<const bf16x8*>(la + _o);                      \
    af[i_][1] = *reinterpret_cast<const bf16x8*>(la + (_o ^ 32));               \
  } while (0)

#define LDB(n_) do {                                                            \
    const int _o = boff + (n_) * 1024;                                          \
    bf_[n_][0] = *reinterpret_cast<const bf16x8*>(lb + _o);                     \
    bf_[n_][1] = *reinterpret_cast<const bf16x8*>(lb + (_o ^ 32));              \
  } while (0)

#define MFMA_PH(mh_, nlo_)                                                      \
  _Pragma("unroll") for (int ks = 0; ks < 2; ++ks)                              \
  _Pragma("unroll") for (int i = 0; i < 4; ++i)                                 \
  _Pragma("unroll") for (int n = 0; n < 2; ++n)                                 \
    acc[(mh_) * 4 + i][(nlo_) + n] = __builtin_amdgcn_mfma_f32_16x16x32_bf16(   \
        af[i][ks], bf_[(nlo_) + n][ks], acc[(mh_) * 4 + i][(nlo_) + n], 0, 0, 0)

  const int KT = Kk >> 6;

  // ---- prologue: tile0 (A0,A1,B0,B1) + tile1 (B0,B1); wait tile0 (vmcnt leaves 4) ----
  STAGE(0, 0, 0, 0); STAGE(0, 0, 1, 0); STAGE(0, 1, 0, 0); STAGE(0, 1, 1, 0);
  STAGE(1, 1, 0, 1); STAGE(1, 1, 1, 1);
  asm volatile("s_waitcnt vmcnt(4)" ::: "memory");
  SCHED0(); BAR();

  for (int kt = 0; kt < KT; ++kt) {
    const int cur = kt & 1;
    const u16* la = &lds[cur][0][0];
    const u16* lb = &lds[cur][1][0];
    const int kt1 = (kt + 1 < KT) ? kt + 1 : KT - 1;   // clamped sources keep
    const int kt2 = (kt + 2 < KT) ? kt + 2 : KT - 1;   // vmcnt counts uniform

    // ---- phase 0: A frags mi0-3 + B frags ni0,1 ; stage [t+1:A half0] ----
    LDA(0, 0); LDA(1, 0); LDA(2, 0); LDA(3, 0);
    LDB(0); LDB(1);
    STAGE(cur ^ 1, 0, 0, kt1);
    SCHED0(); BAR();
    PRIO(1); MFMA_PH(0, 0); PRIO(0);
    SCHED0(); BAR();

    // ---- phase 1: B frags ni2,3 ; stage [t+1:A half1] ----
    LDB(2); LDB(3);
    STAGE(cur ^ 1, 0, 1, kt1);
    SCHED0(); BAR();
    PRIO(1); MFMA_PH(0, 2); PRIO(0);
    SCHED0(); BAR();

    // ---- phase 2: A frags mi4-7 ; stage [t+2:B half0] (cur B0 dead after p1) ----
    LDA(0, 1); LDA(1, 1); LDA(2, 1); LDA(3, 1);
    STAGE(cur, 1, 0, kt2);
    SCHED0(); BAR();
    PRIO(1); MFMA_PH(1, 0); PRIO(0);
    SCHED0(); BAR();

    // ---- phase 3: no reads ; stage [t+2:B half1] ; counted vmcnt(4) ----
    STAGE(cur, 1, 1, kt2);
    PRIO(1); MFMA_PH(1, 2); PRIO(0);
    asm volatile("s_waitcnt vmcnt(4)" ::: "memory");
    SCHED0(); BAR();
  }

  // ---- epilogue: out = acc*scale + bias ----
  const float sc = scale_p[0];
  float bv[4];
#pragma unroll
  for (int ni = 0; ni < 4; ++ni) bv[ni] = bias[n0 + wc * 64 + ni * 16 + r16];
#pragma unroll
  for (int mi = 0; mi < 8; ++mi) {
#pragma unroll
    for (int r = 0; r < 4; ++r) {
      // C/D layout (16x16x32): col = lane&15, row = (lane>>4)*4 + reg
      const int row = m0 + wr * 128 + mi * 16 + kq * 4 + r;
      float* cp = C + (size_t)row * Nn + (n0 + wc * 64 + r16);
#pragma unroll
      for (int ni = 0; ni < 4; ++ni)
        cp[ni * 16] = acc[mi][ni][r] * sc + bv[ni];
    }
  }
#undef STAGE
#undef LDA
#undef LDB
#undef MFMA_PH
}

extern "C" void kernel_launch(void* const* d_in, const int* in_sizes, int n_in,
                              void* d_out, int out_size, void* d_ws, size_t ws_size,
                              hipStream_t stream) {
  (void)n_in; (void)out_size; (void)ws_size;
  const float* x  = (const float*)d_in[0];   // [M][K] fp32
  const float* w  = (const float*)d_in[1];   // [N][K] fp32 (fp8-representable values)
  const float* sc = (const float*)d_in[2];   // [1]
  const float* bs = (const float*)d_in[3];   // [N]
  float* out = (float*)d_out;                // [M][N] fp32

  const int N = in_sizes[3];        // 16384
  const int K = in_sizes[1] / N;    // 4096
  const int M = in_sizes[0] / K;    // 8192

  u16* xb = (u16*)d_ws;                      // [M][K] bf16  (64 MB)
  u16* wb = xb + (size_t)M * K;              // [N][K] bf16  (128 MB)

  cvt_f32_bf16<<<2048, 256, 0, stream>>>(x, xb, (M * K) / 8);
  cvt_f32_bf16<<<2048, 256, 0, stream>>>(w, wb, (N * K) / 8);

  const int NT = N / 256;
  const int nwg = (M / 256) * NT;            // 2048, % 8 == 0
  gemm256_8ph<<<nwg, 512, 0, stream>>>(xb, wb, sc, bs, out, N, K, NT);
}

// Round 3
// 1022.953 us; speedup vs baseline: 1.2398x; 1.0208x over previous
//
#include <hip/hip_runtime.h>
#include <stdint.h>

typedef unsigned short u16;
typedef unsigned int   u32;
using f32x4  = __attribute__((ext_vector_type(4))) float;
using bf16x8 = __attribute__((ext_vector_type(8))) short;   // 8 bf16 codes (4 VGPRs)

// ---------------- fp32 -> bf16 (RNE) conversion, vectorized ----------------
__device__ __forceinline__ u16 f2bf(float f) {
  union { float f; u32 u; } c; c.f = f;
  return (u16)((c.u + 0x7FFFu + ((c.u >> 16) & 1u)) >> 16);
}

__global__ void cvt_f32_bf16(const float* __restrict__ in, u16* __restrict__ out, int n8) {
  int i = blockIdx.x * blockDim.x + threadIdx.x;
  const int stride = gridDim.x * blockDim.x;
  for (; i < n8; i += stride) {
    float4 v0 = reinterpret_cast<const float4*>(in)[2 * i];
    float4 v1 = reinterpret_cast<const float4*>(in)[2 * i + 1];
    uint4 o;
    o.x = (u32)f2bf(v0.x) | ((u32)f2bf(v0.y) << 16);
    o.y = (u32)f2bf(v0.z) | ((u32)f2bf(v0.w) << 16);
    o.z = (u32)f2bf(v1.x) | ((u32)f2bf(v1.y) << 16);
    o.w = (u32)f2bf(v1.z) | ((u32)f2bf(v1.w) << 16);
    reinterpret_cast<uint4*>(out)[i] = o;
  }
}

// async global->LDS, 16B per lane, dest = wave-uniform base + lane*16
#define GLD_LDS16(SRC, DST)                                      \
  __builtin_amdgcn_global_load_lds(                              \
      (const __attribute__((address_space(1))) void*)(SRC),      \
      (__attribute__((address_space(3))) void*)(DST), 16, 0, 0)

#define SCHED0() __builtin_amdgcn_sched_barrier(0)
#define BAR()    __builtin_amdgcn_s_barrier()
#define PRIO(x)  __builtin_amdgcn_s_setprio(x)

// ---------------- 256x256 8-phase bf16 GEMM: C = scale*(A @ B^T) + bias ----------------
// BM=BN=256, BK=64, 8 waves (2M x 4N), per-wave 128x64 output (8x4 16x16 frags).
// LDS: 2 buf x (A 32KB + B 32KB) = 128 KiB. XOR slot swizzle: phys_slot = kslot ^ (row&7),
// staged via inverse-swizzled global source (global_load_lds writes linearly).
// Schedule per K-tile (4 phases, balanced reads {8,4,8,4}):
//   p0: LDA mh0 (8) | stage A-h0(t+1)->buf^1 | BAR | MFMA (mh0 x ni01)
//   p1: LDB ni23 (4)| stage A-h1(t+1)->buf^1 | BAR | MFMA (mh0 x ni23) | BAR
//   p2: LDA mh1 (8) | stage B-h0(t+2)->cur   | BAR | MFMA (mh1 x ni01)
//   p3: vmcnt(6)+BAR (B(t+1) landed) | LDB-next ni01 from buf^1 (4) |
//       stage B-h1(t+2)->cur | MFMA (mh1 x ni23, dep-free) | vmcnt(4)+BAR
__global__ __launch_bounds__(512, 2)
void gemm256_8ph(const u16* __restrict__ A,   // [M][K] bf16
                 const u16* __restrict__ B,   // [N][K] bf16
                 const float* __restrict__ scale_p,
                 const float* __restrict__ bias,
                 float* __restrict__ C,       // [M][N] fp32
                 int Nn, int Kk, int NT) {
  __shared__ u16 lds[2][2][256 * 64];  // [buf][A/B][256 rows x 64 cols]

  const int tid  = threadIdx.x;
  const int lane = tid & 63;
  const int wave = tid >> 6;       // 0..7
  const int wr = wave >> 2;        // 0..1 (M)
  const int wc = wave & 3;         // 0..3 (N)

  // T1: XCD-aware swizzle (gridDim.x == 2048, divisible by 8)
  const int bid = blockIdx.x;
  const int cpx = gridDim.x >> 3;
  const int wg  = (bid & 7) * cpx + (bid >> 3);
  const int mt = wg / NT, nt = wg % NT;
  const int m0 = mt * 256, n0 = nt * 256;

  const int rg  = lane >> 3;             // row in 8-row staging group
  const int ss  = (lane & 7) ^ rg;       // inverse-swizzled source k-slot
  const int r16 = lane & 15;
  const int kq  = lane >> 4;

  // per-thread global staging bases (row = h*128 + wave*16 + j*8 + rg, col = kt*64 + ss*8)
  const u16* ga = A + ((size_t)m0 + wave * 16 + rg) * Kk + ss * 8;
  const u16* gb = B + ((size_t)n0 + wave * 16 + rg) * Kk + ss * 8;

  // LDS element offsets for fragment reads (slot = (ks*4+kq) ^ (row&7); ks flips bit 5)
  const int aoff = (wr * 128 + r16) * 64 + (kq ^ (r16 & 7)) * 8;  // + mi*1024, ^ (ks*32)
  const int boff = (wc * 64  + r16) * 64 + (kq ^ (r16 & 7)) * 8;  // + ni*1024, ^ (ks*32)

  f32x4 acc[8][4];
#pragma unroll
  for (int i = 0; i < 8; ++i)
#pragma unroll
    for (int j = 0; j < 4; ++j)
      acc[i][j] = (f32x4){0.f, 0.f, 0.f, 0.f};

  bf16x8 af[4][2];   // current mi-group (mh*4 + i), ks 0/1 (reused for mh0/mh1)
  bf16x8 bfe[2][2];  // B frags ni0,1 (read one phase early, at prev p3)
  bf16x8 bfo[2][2];  // B frags ni2,3 (same-phase read at p1)

  // stage one half-tile: operand op (0=A,1=B), half h, into buffer bfi_, source k-tile kt
#define STAGE(bfi_, op_, h_, kt_) do {                                          \
    const u16* _g = ((op_) ? gb : ga) + (size_t)(kt_) * 64 + (size_t)(h_) * 128 * Kk; \
    u16* _d = &lds[bfi_][op_][(h_) * 128 * 64 + wave * 16 * 64];                \
    GLD_LDS16(_g,          _d);                                                 \
    GLD_LDS16(_g + 8 * Kk, _d + 512);                                           \
  } while (0)

#define LDA4(la_, mh_) do {                                                     \
    _Pragma("unroll") for (int _i = 0; _i < 4; ++_i) {                          \
      const int _o = aoff + ((mh_) * 4 + _i) * 1024;                            \
      af[_i][0] = *reinterpret_cast<const bf16x8*>((la_) + _o);                 \
      af[_i][1] = *reinterpret_cast<const bf16x8*>((la_) + (_o ^ 32));          \
    } } while (0)

#define LDBE(lb_) do {                                                          \
    _Pragma("unroll") for (int _n = 0; _n < 2; ++_n) {                          \
      const int _o = boff + _n * 1024;                                          \
      bfe[_n][0] = *reinterpret_cast<const bf16x8*>((lb_) + _o);                \
      bfe[_n][1] = *reinterpret_cast<const bf16x8*>((lb_) + (_o ^ 32));         \
    } } while (0)

#define LDBO(lb_) do {                                                          \
    _Pragma("unroll") for (int _n = 0; _n < 2; ++_n) {                          \
      const int _o = boff + (2 + _n) * 1024;                                    \
      bfo[_n][0] = *reinterpret_cast<const bf16x8*>((lb_) + _o);                \
      bfo[_n][1] = *reinterpret_cast<const bf16x8*>((lb_) + (_o ^ 32));         \
    } } while (0)

#define MFMA_Q(mh_, BF_, nb_)                                                   \
  _Pragma("unroll") for (int ks = 0; ks < 2; ++ks)                              \
  _Pragma("unroll") for (int i = 0; i < 4; ++i)                                 \
  _Pragma("unroll") for (int n = 0; n < 2; ++n)                                 \
    acc[(mh_) * 4 + i][(nb_) + n] = __builtin_amdgcn_mfma_f32_16x16x32_bf16(    \
        af[i][ks], BF_[n][ks], acc[(mh_) * 4 + i][(nb_) + n], 0, 0, 0)

  const int KT = Kk >> 6;

  // ---- prologue: tile0 (A0,A1,B0,B1)->buf0 + tile1 (B0,B1)->buf1; drain tile0 ----
  STAGE(0, 0, 0, 0); STAGE(0, 0, 1, 0); STAGE(0, 1, 0, 0); STAGE(0, 1, 1, 0);
  STAGE(1, 1, 0, 1); STAGE(1, 1, 1, 1);
  asm volatile("s_waitcnt vmcnt(4)" ::: "memory");
  SCHED0(); BAR();
  LDBE((const u16*)&lds[0][1][0]);   // pre-read bfe = B01(tile0)

#define TILE(t_, CUR_) do {                                                     \
    const u16* la  = &lds[CUR_][0][0];                                          \
    const u16* lb  = &lds[CUR_][1][0];                                          \
    const u16* lbn = &lds[CUR_ ^ 1][1][0];                                      \
    const int kt1 = ((t_) + 1 < KT) ? (t_) + 1 : KT - 1;                        \
    const int kt2 = ((t_) + 2 < KT) ? (t_) + 2 : KT - 1;                        \
    /* p0 */                                                                    \
    LDA4(la, 0);                                                                \
    STAGE(CUR_ ^ 1, 0, 0, kt1);                                                 \
    SCHED0(); BAR();                                                            \
    PRIO(1); MFMA_Q(0, bfe, 0); PRIO(0);                                        \
    /* p1 */                                                                    \
    LDBO(lb);                                                                   \
    STAGE(CUR_ ^ 1, 0, 1, kt1);                                                 \
    SCHED0(); BAR();                                                            \
    PRIO(1); MFMA_Q(0, bfo, 2); PRIO(0);                                        \
    SCHED0(); BAR();                                                            \
    /* p2 */                                                                    \
    LDA4(la, 1);                                                                \
    STAGE(CUR_, 1, 0, kt2);                                                     \
    SCHED0(); BAR();                                                            \
    PRIO(1); MFMA_Q(1, bfe, 0); PRIO(0);                                        \
    /* p3 */                                                                    \
    asm volatile("s_waitcnt vmcnt(6)" ::: "memory");                            \
    SCHED0(); BAR();                                                            \
    LDBE(lbn);                                                                  \
    STAGE(CUR_, 1, 1, kt2);                                                     \
    PRIO(1); MFMA_Q(1, bfo, 2); PRIO(0);                                        \
    asm volatile("s_waitcnt vmcnt(4)" ::: "memory");                            \
    SCHED0(); BAR();                                                            \
  } while (0)

  for (int kt = 0; kt < KT; kt += 2) {
    TILE(kt, 0);
    TILE(kt + 1, 1);
  }

  // ---- epilogue: out = acc*scale + bias ----
  const float sc = scale_p[0];
  float bv[4];
#pragma unroll
  for (int ni = 0; ni < 4; ++ni) bv[ni] = bias[n0 + wc * 64 + ni * 16 + r16];
#pragma unroll
  for (int mi = 0; mi < 8; ++mi) {
#pragma unroll
    for (int r = 0; r < 4; ++r) {
      // C/D layout (16x16x32): col = lane&15, row = (lane>>4)*4 + reg
      const int row = m0 + wr * 128 + mi * 16 + kq * 4 + r;
      float* cp = C + (size_t)row * Nn + (n0 + wc * 64 + r16);
#pragma unroll
      for (int ni = 0; ni < 4; ++ni)
        cp[ni * 16] = acc[mi][ni][r] * sc + bv[ni];
    }
  }
#undef STAGE
#undef LDA4
#undef LDBE
#undef LDBO
#undef MFMA_Q
#undef TILE
}

extern "C" void kernel_launch(void* const* d_in, const int* in_sizes, int n_in,
                              void* d_out, int out_size, void* d_ws, size_t ws_size,
                              hipStream_t stream) {
  (void)n_in; (void)out_size; (void)ws_size;
  const float* x  = (const float*)d_in[0];   // [M][K] fp32
  const float* w  = (const float*)d_in[1];   // [N][K] fp32 (fp8-representable values)
  const float* sc = (const float*)d_in[2];   // [1]
  const float* bs = (const float*)d_in[3];   // [N]
  float* out = (float*)d_out;                // [M][N] fp32

  const int N = in_sizes[3];        // 16384
  const int K = in_sizes[1] / N;    // 4096
  const int M = in_sizes[0] / K;    // 8192

  u16* xb = (u16*)d_ws;                      // [M][K] bf16  (64 MB)
  u16* wb = xb + (size_t)M * K;              // [N][K] bf16  (128 MB)

  cvt_f32_bf16<<<2048, 256, 0, stream>>>(x, xb, (M * K) / 8);
  cvt_f32_bf16<<<2048, 256, 0, stream>>>(w, wb, (N * K) / 8);

  const int NT = N / 256;
  const int nwg = (M / 256) * NT;            // 2048, % 8 == 0
  gemm256_8ph<<<nwg, 512, 0, stream>>>(xb, wb, sc, bs, out, N, K, NT);
}